// Round 4
// baseline (617.607 us; speedup 1.0000x reference)
//
#include <hip/hip_runtime.h>

// Board: 4096 x 4096 int32 in {0,1,2}  (0=empty, 1=black, 2=white)
// Outputs are BOOLEAN -> int32 (0/1), concatenated flat in d_out:
//   bamboo_b, bamboo_w, tiger_b, tiger_w, etri_b, etri_w  -> each (4095,4095)
//   eye_b, eye_w                                          -> each (4094,4094)
//
// R4 change vs R3: ALL output stores nontemporal (streaming, no L2
// write-allocate). Structure otherwise identical for clean A/B.

#define BW   4096
#define W1   4095
#define W2   4094
#define ROWS 8

typedef int i4u __attribute__((vector_size(16), aligned(4)));   // unaligned store
typedef int i4a __attribute__((vector_size(16), aligned(16)));  // aligned load
typedef int i2a __attribute__((vector_size(8),  aligned(8)));

__global__ __launch_bounds__(256)
void motif_kernel(const int* __restrict__ board, int* __restrict__ out) {
    const int t  = blockIdx.x * 256 + threadIdx.x;  // 0..1023
    const int j0 = t << 2;                          // 0,4,...,4092
    const int i0 = blockIdx.y * ROWS;
    const bool tailj = (j0 == BW - 4);              // last 4-col group

    int c0[6], c1[6], c2[6];                        // rolling row windows

    const int* rp = board + (size_t)i0 * BW + j0;

    auto load6 = [&](const int* p, int* w) {
        i4a v = *(const i4a*)p;                     // 16B aligned (row=16KB, j0%4==0)
        w[0] = v[0]; w[1] = v[1]; w[2] = v[2]; w[3] = v[3];
        if (!tailj) { i2a u = *(const i2a*)(p + 4); w[4] = u[0]; w[5] = u[1]; }
        else        { w[4] = 0; w[5] = 0; }         // cols 4096/4097 don't exist
    };

    load6(rp, c0);          // row i0
    load6(rp + BW, c1);     // row i0+1  (i0 <= 4088 so always in range)

    const int N1 = W1 * W1;
    const int N2 = W2 * W2;

    #pragma unroll
    for (int r = 0; r < ROWS; ++r) {
        const int i = i0 + r;
        if (i >= W1) break;                         // uniform across block
        if (i + 2 < BW)
            load6(board + (size_t)(i + 2) * BW + j0, c2);

        int vb[4], vw[4], vtb[4], vtw[4], veb[4], vew[4], eb[4], ew[4];
        #pragma unroll
        for (int k = 0; k < 4; ++k) {
            const int a = c0[k], b = c0[k + 1], c = c1[k], d = c1[k + 1];
            const int nb_d = (a == 1) + (d == 1), nb_a = (b == 1) + (c == 1);
            const int nw_d = (a == 2) + (d == 2), nw_a = (b == 2) + (c == 2);
            const int ne_d = (a == 0) + (d == 0), ne_a = (b == 0) + (c == 0);
            const int nb = nb_d + nb_a, nw = nw_d + nw_a, ne = ne_d + ne_a;
            vb[k]  = (int)(((nb_d == 2) & (ne_a == 2)) | ((nb_a == 2) & (ne_d == 2)));
            vw[k]  = (int)(((nw_d == 2) & (ne_a == 2)) | ((nw_a == 2) & (ne_d == 2)));
            const int anyE = (int)(ne >= 1);
            vtb[k] = ((int)(nb >= 2)) & anyE;
            vtw[k] = ((int)(nw >= 2)) & anyE;
            veb[k] = (int)((nb == 3) & (ne == 1));
            vew[k] = (int)((nw == 3) & (ne == 1));
            // eye at (i, j0+k): center=c1[k+1], up=b, left=c, down=c2[k+1], right=c1[k+2]
            const int dn = c2[k + 1], rt = c1[k + 2];
            eb[k] = (int)((d == 0) & (b == 1) & (c == 1) & (dn == 1) & (rt == 1));
            ew[k] = (int)((d == 0) & (b == 2) & (c == 2) & (dn == 2) & (rt == 2));
        }

        const int o = i * W1 + j0;
        if (!tailj) {
            i4u s;
            s[0]=vb[0];  s[1]=vb[1];  s[2]=vb[2];  s[3]=vb[3];
            __builtin_nontemporal_store(s, (i4u*)(out + o));
            s[0]=vw[0];  s[1]=vw[1];  s[2]=vw[2];  s[3]=vw[3];
            __builtin_nontemporal_store(s, (i4u*)(out + o + N1));
            s[0]=vtb[0]; s[1]=vtb[1]; s[2]=vtb[2]; s[3]=vtb[3];
            __builtin_nontemporal_store(s, (i4u*)(out + o + 2*N1));
            s[0]=vtw[0]; s[1]=vtw[1]; s[2]=vtw[2]; s[3]=vtw[3];
            __builtin_nontemporal_store(s, (i4u*)(out + o + 3*N1));
            s[0]=veb[0]; s[1]=veb[1]; s[2]=veb[2]; s[3]=veb[3];
            __builtin_nontemporal_store(s, (i4u*)(out + o + 4*N1));
            s[0]=vew[0]; s[1]=vew[1]; s[2]=vew[2]; s[3]=vew[3];
            __builtin_nontemporal_store(s, (i4u*)(out + o + 5*N1));
        } else {
            #pragma unroll
            for (int k = 0; k < 3; ++k) {           // j = 4092..4094 (< W1)
                __builtin_nontemporal_store(vb[k],  out + o + k);
                __builtin_nontemporal_store(vw[k],  out + o + k + N1);
                __builtin_nontemporal_store(vtb[k], out + o + k + 2*N1);
                __builtin_nontemporal_store(vtw[k], out + o + k + 3*N1);
                __builtin_nontemporal_store(veb[k], out + o + k + 4*N1);
                __builtin_nontemporal_store(vew[k], out + o + k + 5*N1);
            }
        }

        if (i < W2) {
            const int o2 = 6 * N1 + i * W2 + j0;
            if (!tailj) {
                i4u s;
                s[0]=eb[0]; s[1]=eb[1]; s[2]=eb[2]; s[3]=eb[3];
                __builtin_nontemporal_store(s, (i4u*)(out + o2));
                s[0]=ew[0]; s[1]=ew[1]; s[2]=ew[2]; s[3]=ew[3];
                __builtin_nontemporal_store(s, (i4u*)(out + o2 + N2));
            } else {                                // j = 4092,4093 (< W2)
                __builtin_nontemporal_store(eb[0], out + o2);
                __builtin_nontemporal_store(eb[1], out + o2 + 1);
                __builtin_nontemporal_store(ew[0], out + o2 + N2);
                __builtin_nontemporal_store(ew[1], out + o2 + N2 + 1);
            }
        }

        #pragma unroll
        for (int q = 0; q < 6; ++q) { c0[q] = c1[q]; c1[q] = c2[q]; }
    }
}

extern "C" void kernel_launch(void* const* d_in, const int* in_sizes, int n_in,
                              void* d_out, int out_size, void* d_ws, size_t ws_size,
                              hipStream_t stream) {
    const int* board = (const int*)d_in[0];
    int* out = (int*)d_out;

    dim3 block(256, 1, 1);
    dim3 grid(4, (W1 + ROWS - 1) / ROWS, 1);   // 4 x 512 blocks
    motif_kernel<<<grid, block, 0, stream>>>(board, out);
}

// Round 5
// 599.030 us; speedup vs baseline: 1.0310x; 1.0310x over previous
//
#include <hip/hip_runtime.h>

// Board: 4096 x 4096 int32 in {0,1,2}  (0=empty, 1=black, 2=white)
// Outputs BOOLEAN -> int32 (0/1), concatenated flat in d_out:
//   bamboo_b, bamboo_w, tiger_b, tiger_w, etri_b, etri_w  -> each (4095,4095)
//   eye_b, eye_w                                          -> each (4094,4094)
//
// R5: all stores forced 16B-aligned by per-plane column phase.
//   plane p base = p*N1, N1 % 4 == 1 ; row offset i*4095 % 4 == (-i)%4
//   -> aligned column phase s_p = (i - p) & 3 for planes 0..5
//   eye planes: base 6*N1 % 4 == 2, row i*4094 % 4 == 2i -> phase e = i odd ? 0 : 2
// Thread u (0..1023) loads aligned board window [4u, 4u+8) of rows i, i+1, i+2,
// computes packed motif masks for window cell positions 0..6 (+eyes 0..5), then
// stores one 16B-aligned dwordx4 per plane at that plane's phase. Head columns
// (< phase) stored scalar by u==0; tail columns by u==1023 (which loads only
// its first, in-bounds dwordx4 per row).

#define BW 4096
#define W1 4095
#define W2 4094
#define N1 16769025   // 4095*4095, % 4 == 1
#define N2 16760836   // 4094*4094, % 4 == 0

typedef int i4a __attribute__((vector_size(16), aligned(16)));

template<int IM4>
__device__ __forceinline__ void store_planes(
    int* __restrict__ out, const int i, const int u, const bool has2,
    const int (&cellm)[7], const int (&eyem)[6])
{
    const bool fullv = (u < 1023);
    const size_t orow = (size_t)i * W1 + (u << 2);

    #pragma unroll
    for (int p = 0; p < 6; ++p) {
        const int sp = (IM4 - p) & 3;          // compile-time after unroll
        int* dst = out + (size_t)p * N1 + orow;
        if (fullv) {
            i4a s;
            s[0] = (cellm[sp + 0] >> p) & 1;
            s[1] = (cellm[sp + 1] >> p) & 1;
            s[2] = (cellm[sp + 2] >> p) & 1;
            s[3] = (cellm[sp + 3] >> p) & 1;
            *(i4a*)(dst + sp) = s;             // 16B-aligned by construction
        } else {                               // u == 1023: cols sp+4092 .. 4094
            #pragma unroll
            for (int k = 0; k < 3 - sp; ++k)
                dst[sp + k] = (cellm[sp + k] >> p) & 1;
        }
        if (u == 0) {                          // head cols 0 .. sp-1
            #pragma unroll
            for (int k = 0; k < sp; ++k)
                dst[k] = (cellm[k] >> p) & 1;
        }
    }

    if (has2) {
        const int e = (IM4 & 1) ? 0 : 2;       // eye phase: i odd -> 0, even -> 2
        int* d0 = out + (size_t)6 * N1 + (size_t)i * W2 + (u << 2);
        int* d1 = d0 + N2;
        if (fullv) {
            i4a s0, s1;
            #pragma unroll
            for (int k = 0; k < 4; ++k) {
                s0[k] =  eyem[e + k]       & 1;
                s1[k] = (eyem[e + k] >> 1) & 1;
            }
            *(i4a*)(d0 + e) = s0;              // 16B-aligned by construction
            *(i4a*)(d1 + e) = s1;
        } else if (e == 0) {                   // u == 1023, cols 4092, 4093
            #pragma unroll
            for (int k = 0; k < 2; ++k) {
                d0[k] =  eyem[k]       & 1;
                d1[k] = (eyem[k] >> 1) & 1;
            }
        }
        if (u == 0) {                          // head cols 0 .. e-1
            #pragma unroll
            for (int k = 0; k < e; ++k) {
                d0[k] =  eyem[k]       & 1;
                d1[k] = (eyem[k] >> 1) & 1;
            }
        }
    }
}

__global__ __launch_bounds__(256)
void motif_kernel(const int* __restrict__ board, int* __restrict__ out) {
    const int u = blockIdx.x * 256 + threadIdx.x;   // 0..1023
    const int i = blockIdx.y;                       // 0..4094
    const int base = u << 2;                        // aligned window start
    const bool fullv = (u < 1023);
    const bool has2  = (i < W2);                    // i <= 4093: eyes + row i+2

    const int* p0 = board + (size_t)i * BW + base;
    const int* p1 = p0 + BW;
    const int* p2 = p1 + BW;

    i4a a0 = *(const i4a*)p0;
    i4a a1 = *(const i4a*)p1;
    i4a b0 = {0, 0, 0, 0}, b1 = {0, 0, 0, 0};
    if (fullv) { b0 = *(const i4a*)(p0 + 4); b1 = *(const i4a*)(p1 + 4); }
    i4a a2 = {0, 0, 0, 0}, b2 = {0, 0, 0, 0};
    if (has2) {
        a2 = *(const i4a*)p2;
        if (fullv) b2 = *(const i4a*)(p2 + 4);
    }

    const int r0[8] = {a0[0], a0[1], a0[2], a0[3], b0[0], b0[1], b0[2], b0[3]};
    const int r1[8] = {a1[0], a1[1], a1[2], a1[3], b1[0], b1[1], b1[2], b1[3]};
    const int r2[8] = {a2[0], a2[1], a2[2], a2[3], b2[0], b2[1], b2[2], b2[3]};

    // Packed motif bits for 2x2 cells at window positions 0..6:
    // bit0 bamboo_b, bit1 bamboo_w, bit2 tiger_b, bit3 tiger_w,
    // bit4 etri_b,   bit5 etri_w
    int cellm[7];
    #pragma unroll
    for (int p = 0; p < 7; ++p) {
        const int a = r0[p], b = r0[p + 1], c = r1[p], d = r1[p + 1];
        const int nb_d = (a == 1) + (d == 1), nb_a = (b == 1) + (c == 1);
        const int nw_d = (a == 2) + (d == 2), nw_a = (b == 2) + (c == 2);
        const int ne_d = (a == 0) + (d == 0), ne_a = (b == 0) + (c == 0);
        const int nb = nb_d + nb_a, nw = nw_d + nw_a, ne = ne_d + ne_a;
        const int bb  = ((nb_d == 2) & (ne_a == 2)) | ((nb_a == 2) & (ne_d == 2));
        const int bw_ = ((nw_d == 2) & (ne_a == 2)) | ((nw_a == 2) & (ne_d == 2));
        const int anyE = (ne >= 1);
        const int tb = (nb >= 2) & anyE;
        const int tw = (nw >= 2) & anyE;
        const int eb = (nb == 3) & (ne == 1);
        const int ew = (nw == 3) & (ne == 1);
        cellm[p] = bb | (bw_ << 1) | (tb << 2) | (tw << 3) | (eb << 4) | (ew << 5);
    }

    // Packed eye bits for positions 0..5: bit0 eye_b, bit1 eye_w
    int eyem[6];
    #pragma unroll
    for (int q = 0; q < 6; ++q) {
        const int ce = r1[q + 1], up = r0[q + 1], lf = r1[q],
                  dn = r2[q + 1], rt = r1[q + 2];
        const int eB = (ce == 0) & (up == 1) & (lf == 1) & (dn == 1) & (rt == 1);
        const int eW = (ce == 0) & (up == 2) & (lf == 2) & (dn == 2) & (rt == 2);
        eyem[q] = eB | (eW << 1);
    }

    switch (i & 3) {  // block-uniform: no divergence
        case 0: store_planes<0>(out, i, u, has2, cellm, eyem); break;
        case 1: store_planes<1>(out, i, u, has2, cellm, eyem); break;
        case 2: store_planes<2>(out, i, u, has2, cellm, eyem); break;
        case 3: store_planes<3>(out, i, u, has2, cellm, eyem); break;
    }
}

extern "C" void kernel_launch(void* const* d_in, const int* in_sizes, int n_in,
                              void* d_out, int out_size, void* d_ws, size_t ws_size,
                              hipStream_t stream) {
    const int* board = (const int*)d_in[0];
    int* out = (int*)d_out;

    dim3 block(256, 1, 1);
    dim3 grid(4, W1, 1);   // 1024 threads cover one output row; 4095 rows
    motif_kernel<<<grid, block, 0, stream>>>(board, out);
}